// Round 11
// baseline (124.121 us; speedup 1.0000x reference)
//
#include <hip/hip_runtime.h>
#include <stdint.h>

// Scaled-dot-product attention. B=4, NQ=NK=4096, D=128, fp32 in/out.
// R12: revert to R6 structure (best measured: attn 51.2us) + VALU diet.
// R11 proved occupancy is NOT binding (2x waves, same per-CU throughput,
// 2x L2 traffic). R6's VALUBusy 28.7% @ 2 waves/SIMD ~= 550 VALU cy/wave/iter:
// cut it with (1) v_cvt_pk_bf16_f32 for the P bf16 pack (1 instr per pair vs
// ~5 for hand-rolled pk2bf; RNE rounding, numerically fine), (2) s_setprio(1)
// around MFMA clusters (T5: +4-7% on phase-staggered attn waves).
// Everything else byte-identical to R6: frag-major K/V global->reg 2-deep A/B
// prefetch, double-buffered LDS P exchange, ONE raw s_barrier per iter
// (lgkmcnt-only drain; K/V loads stay in flight across it).
#define B_ 4
#define NQ_ 4096
#define NK_ 4096
#define D_ 128
#define BM_ 64
#define BN_ 128
#define NITER_ (NK_/BN_)
#define PS_ 136        // P row stride (shorts): 272 B, 16B-aligned reads, 2-way (free)
#define OS_ 66         // epilogue O region row stride (floats)

typedef __attribute__((ext_vector_type(8))) short short8;
typedef __attribute__((ext_vector_type(4))) float floatx4;
typedef unsigned int u32;

union frag_u { u32 u[4]; short8 s; };
union pair_u { u32 u[2]; uint2 v; };

__device__ __forceinline__ unsigned short f2bf_rne(float x){
  union { float f; u32 u; } c; c.f = x;
  u32 u = c.u;
  return (unsigned short)((u + 0x7fffu + ((u >> 16) & 1u)) >> 16);
}
// pack 2 f32 -> 2 bf16 (round-half-up; bias << bf16 quantization)
__device__ __forceinline__ u32 pk2bf(float a, float b){
  union { float f; u32 u; } x, y; x.f = a; y.f = b;
  return ((x.u + 0x8000u) >> 16) | ((y.u + 0x8000u) & 0xffff0000u);
}
// single-instruction 2xf32 -> bf16x2 (RNE); gfx950 has no builtin (m240)
__device__ __forceinline__ u32 cvtpk(float lo, float hi){
  u32 r;
  asm("v_cvt_pk_bf16_f32 %0, %1, %2" : "=v"(r) : "v"(lo), "v"(hi));
  return r;
}

// ---- prep (unchanged from R7) ----
// Fragment layouts:
//  Kf chunk flat = (((b*32+it)*8 + wq)*4 + j)*64 + lane : 8 shorts =
//     K[b][it*128 + kg*32 + (l15>>2)*8 + dh*4 + (l15&3)][j*32 + l4*8 .. +8]
//  Vf chunk flat = (((b*32+it)*8 + w)*4 + dt)*64 + lane : short kk(0..7) =
//     V[b][it*128 + kg*32 + l4*8 + kk][dh*64 + dt*16 + l15]
__global__ __launch_bounds__(256) void prep_kernel(
    const float* __restrict__ k, const float* __restrict__ v,
    unsigned short* __restrict__ kf, unsigned short* __restrict__ vf){
  __shared__ __align__(16) char smem[40960];
  const int t = threadIdx.x;
  const int blk = blockIdx.x;
  if (blk < 128){
    // ---------------- K part ----------------
    int b = blk >> 5, it = blk & 31;
    const float* src = k + ((size_t)b*NK_ + it*BN_)*D_;
    #pragma unroll
    for (int i = 0; i < 16; i++){
      int f = t + i*256;                 // 0..4095 float4s
      int row = f >> 5, c4 = f & 31;     // row = local key, c4*4 = d
      float4 a = *(const float4*)(src + (size_t)row*D_ + c4*4);
      ushort4 s;
      s.x = f2bf_rne(a.x); s.y = f2bf_rne(a.y);
      s.z = f2bf_rne(a.z); s.w = f2bf_rne(a.w);
      int kg = row >> 5, rem = row & 31;
      int dh = (rem >> 2) & 1;
      int l15 = ((rem >> 3) << 2) | (rem & 3);
      int wq = kg*2 + dh;
      int j = c4 >> 3, l4 = (c4 >> 1) & 3, half = c4 & 1;
      *(ushort4*)(smem + (wq*4 + j)*1088 + l4*272 + l15*16 + half*8) = s;
    }
    __syncthreads();
    unsigned short* dst = kf + (size_t)(b*32 + it)*2048*8;
    #pragma unroll
    for (int i = 0; i < 8; i++){
      int c = t + i*256;                 // 0..2047 chunks
      int lane = c & 63, j = (c >> 6) & 3, wq = c >> 8;
      int l15 = lane & 15, l4 = lane >> 4;
      short8 x = *(const short8*)(smem + (wq*4 + j)*1088 + l4*272 + l15*16);
      *(short8*)(dst + (size_t)c*8) = x;
    }
  } else {
    // ---------------- V part ----------------
    int blk2 = blk - 128;
    int b = blk2 >> 5, it = blk2 & 31;
    const float* src = v + ((size_t)b*NK_ + it*BN_)*D_;
    #pragma unroll
    for (int i = 0; i < 16; i++){
      int f = t + i*256;
      int row = f >> 5, c4 = f & 31;
      float4 a = *(const float4*)(src + (size_t)row*D_ + c4*4);
      float vals[4] = {a.x, a.y, a.z, a.w};
      int kk = row & 7, l4a = (row >> 3) & 3, kga = row >> 5;
      #pragma unroll
      for (int jj = 0; jj < 4; jj++){
        int d = c4*4 + jj;
        int dh = d >> 6, dt = (d >> 4) & 3, l15 = d & 15;
        int c = ((kga*2 + dh)*4 + dt)*64 + l4a*16 + l15;
        *(unsigned short*)(smem + c*16 + (c>>2)*16 + kk*2) = f2bf_rne(vals[jj]);
      }
    }
    __syncthreads();
    unsigned short* dst = vf + (size_t)(b*32 + it)*2048*8;
    #pragma unroll
    for (int i = 0; i < 8; i++){
      int c = t + i*256;
      short8 x = *(const short8*)(smem + c*16 + (c>>2)*16);
      *(short8*)(dst + (size_t)c*8) = x;
    }
  }
}

// ---- main kernel ----
// grid 256 = B*NQ/64 (batch constant per XCD-pair -> K/V L2-resident);
// block 512 = 8 waves = (kg:4 key-groups) x (dh:2 d-halves).
// Wave (kg,dh): S^T for its 16 keys x 64 q-rows via mfma(K,Q); P exchanged via
// double-buffered LDS; raw s_barrier (no vmcnt drain) once per iter; K/V
// fragment loads 2 tiles deep in A/B register sets (issued after last use).
__global__ __launch_bounds__(512, 2) void attn_kernel(
    const float* __restrict__ Qf, const unsigned short* __restrict__ Kb,
    const unsigned short* __restrict__ Vt, float* __restrict__ Out){
  __shared__ __align__(16) char sm[69632];
  unsigned short* smP = (unsigned short*)sm;      // 2 x 64 x PS_ shorts = 34816 B
  float* smO = (float*)sm;                        // epilogue alias: 4 x 64 x OS_ floats
  float* smL = (float*)(sm + 67584);              // 8 x 64 f32 = 2048 B

  const int bi = blockIdx.x;
  const int b  = (bi >> 1) & 3;                 // batch constant per XCD-pair
  const int qt = ((bi >> 3) << 1) | (bi & 1);
  const int q0 = qt * BM_;
  const int tid = threadIdx.x;
  const int w = tid >> 6, lane = tid & 63;
  const int kg = w >> 1, dh = w & 1;
  const int l15 = lane & 15, l4 = lane >> 4;

  const short8* Kfrag = (const short8*)Kb;
  const short8* Vfrag = (const short8*)Vt;
  const size_t FSTRIDE = 8*4*64;                 // short8 units per K-tile iter
  const size_t fbase = (((size_t)b*32)*8 + w)*4*64 + lane;

  // ---- Q fragments direct from fp32 global ----
  short8 qf[4][4];
  {
    const float* qp = Qf + ((size_t)b*NQ_ + q0)*D_;
    #pragma unroll
    for (int nb = 0; nb < 4; nb++)
      #pragma unroll
      for (int kbq = 0; kbq < 4; kbq++){
        const float* p = qp + (size_t)(nb*16 + l15)*D_ + kbq*32 + l4*8;
        float4 a = *(const float4*)p;
        float4 c4 = *(const float4*)(p + 4);
        frag_u f;
        f.u[0] = pk2bf(a.x, a.y);  f.u[1] = pk2bf(a.z, a.w);
        f.u[2] = pk2bf(c4.x, c4.y); f.u[3] = pk2bf(c4.z, c4.w);
        qf[nb][kbq] = f.s;
      }
  }

  // ---- prologue: A set <- tile 0, B set <- tile 1 ----
  short8 kfA[4], kfB[4], vfA[4], vfB[4];
  #pragma unroll
  for (int j = 0; j < 4; j++) kfA[j] = Kfrag[fbase + j*64];
  #pragma unroll
  for (int dt = 0; dt < 4; dt++) vfA[dt] = Vfrag[fbase + dt*64];
  #pragma unroll
  for (int j = 0; j < 4; j++) kfB[j] = Kfrag[fbase + FSTRIDE + j*64];
  #pragma unroll
  for (int dt = 0; dt < 4; dt++) vfB[dt] = Vfrag[fbase + FSTRIDE + dt*64];

  floatx4 o[4][4];
  #pragma unroll
  for (int nb = 0; nb < 4; nb++)
    #pragma unroll
    for (int dt = 0; dt < 4; dt++) o[nb][dt] = (floatx4)0.0f;
  float lsum[4] = {0.f, 0.f, 0.f, 0.f};

  const float SL = 0.08838834764831845f * 1.4426950408889634f; // 1/sqrt(128)*log2(e)
  const size_t prow = (size_t)kg*32 + l4*8;

  for (int it = 0; it < NITER_; it += 2){
    // ================= even sub-iter: consume A (tile it) =================
    {
      floatx4 s[4];
      __builtin_amdgcn_s_setprio(1);
      #pragma unroll
      for (int nb = 0; nb < 4; nb++){
        s[nb] = (floatx4)0.0f;
        s[nb] = __builtin_amdgcn_mfma_f32_16x16x32_bf16(kfA[0], qf[nb][0], s[nb], 0,0,0);
        s[nb] = __builtin_amdgcn_mfma_f32_16x16x32_bf16(kfA[1], qf[nb][1], s[nb], 0,0,0);
        s[nb] = __builtin_amdgcn_mfma_f32_16x16x32_bf16(kfA[2], qf[nb][2], s[nb], 0,0,0);
        s[nb] = __builtin_amdgcn_mfma_f32_16x16x32_bf16(kfA[3], qf[nb][3], s[nb], 0,0,0);
      }
      __builtin_amdgcn_s_setprio(0);
      // prefetch K(it+2) -> A (kfA dead after S-phase)
      if (it + 2 < NITER_){
        #pragma unroll
        for (int j = 0; j < 4; j++)
          kfA[j] = Kfrag[fbase + (size_t)(it+2)*FSTRIDE + j*64];
      }
      unsigned short* smPb = smP;   // buf 0
      #pragma unroll
      for (int nb = 0; nb < 4; nb++){
        float p0 = __builtin_amdgcn_exp2f(s[nb][0] * SL);
        float p1 = __builtin_amdgcn_exp2f(s[nb][1] * SL);
        float p2 = __builtin_amdgcn_exp2f(s[nb][2] * SL);
        float p3 = __builtin_amdgcn_exp2f(s[nb][3] * SL);
        lsum[nb] += (p0 + p1) + (p2 + p3);
        pair_u pp; pp.u[0] = cvtpk(p0, p1); pp.u[1] = cvtpk(p2, p3);
        *(uint2*)(smPb + (size_t)(nb*16 + l15)*PS_ + prow + dh*4) = pp.v;
      }
      asm volatile("s_waitcnt lgkmcnt(0)" ::: "memory");
      __builtin_amdgcn_s_barrier();
      asm volatile("" ::: "memory");
      short8 pf[4];
      #pragma unroll
      for (int nb = 0; nb < 4; nb++)
        pf[nb] = *(const short8*)(smPb + (size_t)(nb*16 + l15)*PS_ + prow);
      __builtin_amdgcn_s_setprio(1);
      #pragma unroll
      for (int nb = 0; nb < 4; nb++)
        #pragma unroll
        for (int dt = 0; dt < 4; dt++)
          o[nb][dt] = __builtin_amdgcn_mfma_f32_16x16x32_bf16(pf[nb], vfA[dt], o[nb][dt], 0,0,0);
      __builtin_amdgcn_s_setprio(0);
      // prefetch V(it+2) -> A (vfA dead after PV)
      if (it + 2 < NITER_){
        #pragma unroll
        for (int dt = 0; dt < 4; dt++)
          vfA[dt] = Vfrag[fbase + (size_t)(it+2)*FSTRIDE + dt*64];
      }
    }
    // ================= odd sub-iter: consume B (tile it+1) =================
    {
      floatx4 s[4];
      __builtin_amdgcn_s_setprio(1);
      #pragma unroll
      for (int nb = 0; nb < 4; nb++){
        s[nb] = (floatx4)0.0f;
        s[nb] = __builtin_amdgcn_mfma_f32_16x16x32_bf16(kfB[0], qf[nb][0], s[nb], 0,0,0);
        s[nb] = __builtin_amdgcn_mfma_f32_16x16x32_bf16(kfB[1], qf[nb][1], s[nb], 0,0,0);
        s[nb] = __builtin_amdgcn_mfma_f32_16x16x32_bf16(kfB[2], qf[nb][2], s[nb], 0,0,0);
        s[nb] = __builtin_amdgcn_mfma_f32_16x16x32_bf16(kfB[3], qf[nb][3], s[nb], 0,0,0);
      }
      __builtin_amdgcn_s_setprio(0);
      if (it + 3 < NITER_){
        #pragma unroll
        for (int j = 0; j < 4; j++)
          kfB[j] = Kfrag[fbase + (size_t)(it+3)*FSTRIDE + j*64];
      }
      unsigned short* smPb = smP + 64*PS_;   // buf 1
      #pragma unroll
      for (int nb = 0; nb < 4; nb++){
        float p0 = __builtin_amdgcn_exp2f(s[nb][0] * SL);
        float p1 = __builtin_amdgcn_exp2f(s[nb][1] * SL);
        float p2 = __builtin_amdgcn_exp2f(s[nb][2] * SL);
        float p3 = __builtin_amdgcn_exp2f(s[nb][3] * SL);
        lsum[nb] += (p0 + p1) + (p2 + p3);
        pair_u pp; pp.u[0] = cvtpk(p0, p1); pp.u[1] = cvtpk(p2, p3);
        *(uint2*)(smPb + (size_t)(nb*16 + l15)*PS_ + prow + dh*4) = pp.v;
      }
      asm volatile("s_waitcnt lgkmcnt(0)" ::: "memory");
      __builtin_amdgcn_s_barrier();
      asm volatile("" ::: "memory");
      short8 pf[4];
      #pragma unroll
      for (int nb = 0; nb < 4; nb++)
        pf[nb] = *(const short8*)(smPb + (size_t)(nb*16 + l15)*PS_ + prow);
      __builtin_amdgcn_s_setprio(1);
      #pragma unroll
      for (int nb = 0; nb < 4; nb++)
        #pragma unroll
        for (int dt = 0; dt < 4; dt++)
          o[nb][dt] = __builtin_amdgcn_mfma_f32_16x16x32_bf16(pf[nb], vfB[dt], o[nb][dt], 0,0,0);
      __builtin_amdgcn_s_setprio(0);
      if (it + 3 < NITER_){
        #pragma unroll
        for (int dt = 0; dt < 4; dt++)
          vfB[dt] = Vfrag[fbase + (size_t)(it+3)*FSTRIDE + dt*64];
      }
    }
  }

  // ---- epilogue: l reduce (once), O reduce over 4 key-groups, normalize, store ----
  #pragma unroll
  for (int nb = 0; nb < 4; nb++){
    float v = lsum[nb];
    v += __shfl_xor(v, 16);
    v += __shfl_xor(v, 32);
    lsum[nb] = v;
  }
  if (l4 == 0)
    #pragma unroll
    for (int nb = 0; nb < 4; nb++)
      smL[w*64 + nb*16 + l15] = lsum[nb];

  __syncthreads();   // all last-iter P reads done before smO aliases the P region

  if (w >= 4){
    float* r = smO + (size_t)(w - 4) * 4224;
    #pragma unroll
    for (int nb = 0; nb < 4; nb++)
      #pragma unroll
      for (int dt = 0; dt < 4; dt++)
        #pragma unroll
        for (int q = 0; q < 4; q++)
          r[(size_t)(nb*16 + l4*4 + q)*OS_ + dt*16 + l15] = o[nb][dt][q];
  }
  __syncthreads();
  if (w < 4){
    float* r = smO + (size_t)w * 4224;
    #pragma unroll
    for (int nb = 0; nb < 4; nb++)
      #pragma unroll
      for (int dt = 0; dt < 4; dt++)
        #pragma unroll
        for (int q = 0; q < 4; q++)
          o[nb][dt][q] += r[(size_t)(nb*16 + l4*4 + q)*OS_ + dt*16 + l15];
  }
  __syncthreads();
  if (w == 2 || w == 3){
    float* r = smO + (size_t)(w - 2) * 4224;
    #pragma unroll
    for (int nb = 0; nb < 4; nb++)
      #pragma unroll
      for (int dt = 0; dt < 4; dt++)
        #pragma unroll
        for (int q = 0; q < 4; q++)
          r[(size_t)(nb*16 + l4*4 + q)*OS_ + dt*16 + l15] = o[nb][dt][q];
  }
  __syncthreads();
  if (w < 2){
    float* r = smO + (size_t)w * 4224;
    float* og = Out + ((size_t)b*NQ_ + q0)*D_ + dh*64;
    #pragma unroll
    for (int nb = 0; nb < 4; nb++)
      #pragma unroll
      for (int q = 0; q < 4; q++){
        int row = nb*16 + l4*4 + q;
        float lt = 0.f;
        #pragma unroll
        for (int w2 = 0; w2 < 8; w2++) lt += smL[w2*64 + row];
        float inv = 1.0f / lt;
        #pragma unroll
        for (int dt = 0; dt < 4; dt++){
          float val = o[nb][dt][q] + r[(size_t)row*OS_ + dt*16 + l15];
          og[(size_t)row*D_ + dt*16 + l15] = val * inv;
        }
      }
  }
}

extern "C" void kernel_launch(void* const* d_in, const int* in_sizes, int n_in,
                              void* d_out, int out_size, void* d_ws, size_t ws_size,
                              hipStream_t stream){
  const float* q = (const float*)d_in[0];   // target [4,4096,128]
  const float* k = (const float*)d_in[1];   // key    [4,4096,128]
  const float* v = (const float*)d_in[2];   // value  [4,4096,128]
  float* out = (float*)d_out;
  unsigned short* kb = (unsigned short*)d_ws;          // K frag-major bf16, 4 MiB
  unsigned short* vt = kb + (size_t)B_*NK_*D_;         // V frag-major bf16, 4 MiB
  prep_kernel<<<256, 256, 0, stream>>>(k, v, kb, vt);
  attn_kernel<<<256, 512, 0, stream>>>(q, kb, vt, out);
}

// Round 12
// 123.704 us; speedup vs baseline: 1.0034x; 1.0034x over previous
//
#include <hip/hip_runtime.h>
#include <stdint.h>

// Scaled-dot-product attention. B=4, NQ=NK=4096, D=128, fp32 in/out.
// R13: 16-wave block at constant traffic. R11 falsified "occupancy helps"
// only because BM=32 doubled per-CU L2 traffic; R12's cvtpk/setprio caused
// minor spills (FETCH canary) and regressed. This round: BM=64 kept (same
// reuse), block = 1024 threads = 16 waves = (qh:2)x(kg:4)x(dh:2); each wave
// does HALF of an R6 wave's work (S: 16 keys x 32 q = 8 MFMA; PV: 32 keys x
// 32 q x d-half = 8 MFMA) -> per-wave regs ~120 <= 128 -> all 16 waves
// resident = 4 waves/SIMD = 2x TLP at IDENTICAL per-CU traffic and work.
// Same frag-major layouts, double-buffered P exchange, one raw s_barrier
// per iter (lgkmcnt-only), K/V single-buffer prefetch after last use.
// Spill canary: FETCH_SIZE must stay ~12.4MB.
#define B_ 4
#define NQ_ 4096
#define NK_ 4096
#define D_ 128
#define BM_ 64
#define BN_ 128
#define NITER_ (NK_/BN_)
#define PS_ 136        // P row stride (shorts): 272 B
#define OS_ 66         // epilogue O region row stride (floats)

typedef __attribute__((ext_vector_type(8))) short short8;
typedef __attribute__((ext_vector_type(4))) float floatx4;
typedef unsigned int u32;

union frag_u { u32 u[4]; short8 s; };
union pair_u { u32 u[2]; uint2 v; };

__device__ __forceinline__ unsigned short f2bf_rne(float x){
  union { float f; u32 u; } c; c.f = x;
  u32 u = c.u;
  return (unsigned short)((u + 0x7fffu + ((u >> 16) & 1u)) >> 16);
}
// pack 2 f32 -> 2 bf16 (round-half-up; bias << bf16 quantization)
__device__ __forceinline__ u32 pk2bf(float a, float b){
  union { float f; u32 u; } x, y; x.f = a; y.f = b;
  return ((x.u + 0x8000u) >> 16) | ((y.u + 0x8000u) & 0xffff0000u);
}

// ---- prep (unchanged from R7) ----
// Fragment layouts:
//  Kf chunk flat = (((b*32+it)*8 + wq)*4 + j)*64 + lane : 8 shorts =
//     K[b][it*128 + kg*32 + (l15>>2)*8 + dh*4 + (l15&3)][j*32 + l4*8 .. +8]
//  Vf chunk flat = (((b*32+it)*8 + wq)*4 + dt)*64 + lane : short kk(0..7) =
//     V[b][it*128 + kg*32 + l4*8 + kk][dh*64 + dt*16 + l15]   (wq = kg*2+dh)
__global__ __launch_bounds__(256) void prep_kernel(
    const float* __restrict__ k, const float* __restrict__ v,
    unsigned short* __restrict__ kf, unsigned short* __restrict__ vf){
  __shared__ __align__(16) char smem[40960];
  const int t = threadIdx.x;
  const int blk = blockIdx.x;
  if (blk < 128){
    // ---------------- K part ----------------
    int b = blk >> 5, it = blk & 31;
    const float* src = k + ((size_t)b*NK_ + it*BN_)*D_;
    #pragma unroll
    for (int i = 0; i < 16; i++){
      int f = t + i*256;                 // 0..4095 float4s
      int row = f >> 5, c4 = f & 31;     // row = local key, c4*4 = d
      float4 a = *(const float4*)(src + (size_t)row*D_ + c4*4);
      ushort4 s;
      s.x = f2bf_rne(a.x); s.y = f2bf_rne(a.y);
      s.z = f2bf_rne(a.z); s.w = f2bf_rne(a.w);
      int kg = row >> 5, rem = row & 31;
      int dh = (rem >> 2) & 1;
      int l15 = ((rem >> 3) << 2) | (rem & 3);
      int wq = kg*2 + dh;
      int j = c4 >> 3, l4 = (c4 >> 1) & 3, half = c4 & 1;
      *(ushort4*)(smem + (wq*4 + j)*1088 + l4*272 + l15*16 + half*8) = s;
    }
    __syncthreads();
    unsigned short* dst = kf + (size_t)(b*32 + it)*2048*8;
    #pragma unroll
    for (int i = 0; i < 8; i++){
      int c = t + i*256;                 // 0..2047 chunks
      int lane = c & 63, j = (c >> 6) & 3, wq = c >> 8;
      int l15 = lane & 15, l4 = lane >> 4;
      short8 x = *(const short8*)(smem + (wq*4 + j)*1088 + l4*272 + l15*16);
      *(short8*)(dst + (size_t)c*8) = x;
    }
  } else {
    // ---------------- V part ----------------
    int blk2 = blk - 128;
    int b = blk2 >> 5, it = blk2 & 31;
    const float* src = v + ((size_t)b*NK_ + it*BN_)*D_;
    #pragma unroll
    for (int i = 0; i < 16; i++){
      int f = t + i*256;
      int row = f >> 5, c4 = f & 31;
      float4 a = *(const float4*)(src + (size_t)row*D_ + c4*4);
      float vals[4] = {a.x, a.y, a.z, a.w};
      int kk = row & 7, l4a = (row >> 3) & 3, kga = row >> 5;
      #pragma unroll
      for (int jj = 0; jj < 4; jj++){
        int d = c4*4 + jj;
        int dh = d >> 6, dt = (d >> 4) & 3, l15 = d & 15;
        int c = ((kga*2 + dh)*4 + dt)*64 + l4a*16 + l15;
        *(unsigned short*)(smem + c*16 + (c>>2)*16 + kk*2) = f2bf_rne(vals[jj]);
      }
    }
    __syncthreads();
    unsigned short* dst = vf + (size_t)(b*32 + it)*2048*8;
    #pragma unroll
    for (int i = 0; i < 8; i++){
      int c = t + i*256;
      short8 x = *(const short8*)(smem + c*16 + (c>>2)*16);
      *(short8*)(dst + (size_t)c*8) = x;
    }
  }
}

// ---- main kernel ----
// grid 256 = B*NQ/64 (batch constant per XCD-pair); block 1024 = 16 waves =
// (qh:2 q-halves) x (kg:4 key-groups) x (dh:2 d-halves). Wave (qh,kg,dh):
// S^T for 16 keys (group wq=kg*2+dh) x 32 q-rows (half qh); P exchanged via
// double-buffered LDS (one raw barrier/iter); PV over kg's 32 keys, d-half dh,
// q-half qh. K/V frag loads single-buffered, prefetched after last use.
__global__ __launch_bounds__(1024) void attn_kernel(
    const float* __restrict__ Qf, const unsigned short* __restrict__ Kb,
    const unsigned short* __restrict__ Vt, float* __restrict__ Out){
  __shared__ __align__(16) char sm[69632];
  unsigned short* smP = (unsigned short*)sm;      // 2 x 64 x PS_ shorts = 34816 B
  float* smO = (float*)sm;                        // epilogue alias: 8 x 32 x OS_ floats = 67584 B
  float* smL = (float*)(sm + 67584);              // 8 wq x 64 rows f32 = 2048 B

  const int bi = blockIdx.x;
  const int b  = (bi >> 1) & 3;                 // batch constant per XCD-pair
  const int qt = ((bi >> 3) << 1) | (bi & 1);
  const int q0 = qt * BM_;
  const int tid = threadIdx.x;
  const int w = tid >> 6, lane = tid & 63;
  const int qh = w >> 3;                        // q-half 0/1
  const int kg = (w >> 1) & 3;                  // key group
  const int dh = w & 1;                         // d-half (and wq sub-group)
  const int wq = w & 7;                         // K/V fragment group
  const int l15 = lane & 15, l4 = lane >> 4;

  const short8* Kfrag = (const short8*)Kb;
  const short8* Vfrag = (const short8*)Vt;
  const size_t FSTRIDE = 8*4*64;                // short8 units per K-tile iter
  const size_t fbase = (((size_t)b*32)*8 + wq)*4*64 + lane;

  // ---- Q fragments (32 q-rows of half qh) ----
  short8 qf[2][4];
  {
    const float* qp = Qf + ((size_t)b*NQ_ + q0 + qh*32)*D_;
    #pragma unroll
    for (int n = 0; n < 2; n++)
      #pragma unroll
      for (int kbq = 0; kbq < 4; kbq++){
        const float* p = qp + (size_t)(n*16 + l15)*D_ + kbq*32 + l4*8;
        float4 a = *(const float4*)p;
        float4 c4 = *(const float4*)(p + 4);
        frag_u f;
        f.u[0] = pk2bf(a.x, a.y);  f.u[1] = pk2bf(a.z, a.w);
        f.u[2] = pk2bf(c4.x, c4.y); f.u[3] = pk2bf(c4.z, c4.w);
        qf[n][kbq] = f.s;
      }
  }

  // ---- prologue: tile 0 into single K/V register buffers ----
  short8 kf[4], vf[4];
  #pragma unroll
  for (int j = 0; j < 4; j++) kf[j] = Kfrag[fbase + j*64];
  #pragma unroll
  for (int dt = 0; dt < 4; dt++) vf[dt] = Vfrag[fbase + dt*64];

  floatx4 o[2][4];
  #pragma unroll
  for (int n = 0; n < 2; n++)
    #pragma unroll
    for (int dt = 0; dt < 4; dt++) o[n][dt] = (floatx4)0.0f;
  float lsum[2] = {0.f, 0.f};

  const float SL = 0.08838834764831845f * 1.4426950408889634f; // 1/sqrt(128)*log2(e)
  const size_t prow = (size_t)kg*32 + l4*8;

  for (int it = 0; it < NITER_; ++it){
    // ---- S^T: group wq's 16 keys x 32 q-rows ----
    floatx4 s[2];
    #pragma unroll
    for (int n = 0; n < 2; n++){
      s[n] = (floatx4)0.0f;
      s[n] = __builtin_amdgcn_mfma_f32_16x16x32_bf16(kf[0], qf[n][0], s[n], 0,0,0);
      s[n] = __builtin_amdgcn_mfma_f32_16x16x32_bf16(kf[1], qf[n][1], s[n], 0,0,0);
      s[n] = __builtin_amdgcn_mfma_f32_16x16x32_bf16(kf[2], qf[n][2], s[n], 0,0,0);
      s[n] = __builtin_amdgcn_mfma_f32_16x16x32_bf16(kf[3], qf[n][3], s[n], 0,0,0);
    }
    // prefetch K(it+1) (kf dead after S)
    if (it + 1 < NITER_){
      #pragma unroll
      for (int j = 0; j < 4; j++)
        kf[j] = Kfrag[fbase + (size_t)(it+1)*FSTRIDE + j*64];
    }
    // ---- p = exp2(s*SL); write P; accum l ----
    unsigned short* smPb = smP + (it & 1) * (64 * PS_);
    #pragma unroll
    for (int n = 0; n < 2; n++){
      float p0 = __builtin_amdgcn_exp2f(s[n][0] * SL);
      float p1 = __builtin_amdgcn_exp2f(s[n][1] * SL);
      float p2 = __builtin_amdgcn_exp2f(s[n][2] * SL);
      float p3 = __builtin_amdgcn_exp2f(s[n][3] * SL);
      lsum[n] += (p0 + p1) + (p2 + p3);
      pair_u pp; pp.u[0] = pk2bf(p0, p1); pp.u[1] = pk2bf(p2, p3);
      // row = qh*32 + n*16 + l15; col = kg*32 + l4*8 + dh*4
      *(uint2*)(smPb + (size_t)(qh*32 + n*16 + l15)*PS_ + prow + dh*4) = pp.v;
    }
    asm volatile("s_waitcnt lgkmcnt(0)" ::: "memory");
    __builtin_amdgcn_s_barrier();
    asm volatile("" ::: "memory");
    // ---- O += P V : kg's 32 keys, d-half dh, q-half qh ----
    #pragma unroll
    for (int n = 0; n < 2; n++){
      short8 pf = *(const short8*)(smPb + (size_t)(qh*32 + n*16 + l15)*PS_ + prow);
      o[n][0] = __builtin_amdgcn_mfma_f32_16x16x32_bf16(pf, vf[0], o[n][0], 0,0,0);
      o[n][1] = __builtin_amdgcn_mfma_f32_16x16x32_bf16(pf, vf[1], o[n][1], 0,0,0);
      o[n][2] = __builtin_amdgcn_mfma_f32_16x16x32_bf16(pf, vf[2], o[n][2], 0,0,0);
      o[n][3] = __builtin_amdgcn_mfma_f32_16x16x32_bf16(pf, vf[3], o[n][3], 0,0,0);
    }
    // prefetch V(it+1) (vf dead after PV)
    if (it + 1 < NITER_){
      #pragma unroll
      for (int dt = 0; dt < 4; dt++)
        vf[dt] = Vfrag[fbase + (size_t)(it+1)*FSTRIDE + dt*64];
    }
    // next iter writes the other P buffer; buffer reuse at it+2 is fenced
    // by the barrier at it+1 (this wave's LDS reads drained by its lgkmcnt).
  }

  // ---- epilogue: l reduce; O reduce over kg (4 partials); normalize; store ----
  #pragma unroll
  for (int n = 0; n < 2; n++){
    float v = lsum[n];
    v += __shfl_xor(v, 16);
    v += __shfl_xor(v, 32);
    lsum[n] = v;
  }
  if (l4 == 0)
    #pragma unroll
    for (int n = 0; n < 2; n++)
      smL[wq*64 + qh*32 + n*16 + l15] = lsum[n];

  __syncthreads();   // last P reads done before smO aliases the P region

  const int g = qh*2 + dh;   // (q-half, d-half) quadrant 0..3
  if (kg >= 2){
    float* r = smO + (size_t)(g*2 + (kg-2)) * 2112;
    #pragma unroll
    for (int n = 0; n < 2; n++)
      #pragma unroll
      for (int dt = 0; dt < 4; dt++)
        #pragma unroll
        for (int q = 0; q < 4; q++)
          r[(size_t)(n*16 + l4*4 + q)*OS_ + dt*16 + l15] = o[n][dt][q];
  }
  __syncthreads();
  if (kg < 2){
    float* r = smO + (size_t)(g*2 + kg) * 2112;
    #pragma unroll
    for (int n = 0; n < 2; n++)
      #pragma unroll
      for (int dt = 0; dt < 4; dt++)
        #pragma unroll
        for (int q = 0; q < 4; q++)
          o[n][dt][q] += r[(size_t)(n*16 + l4*4 + q)*OS_ + dt*16 + l15];
  }
  __syncthreads();
  if (kg == 1){
    float* r = smO + (size_t)g * 2112;
    #pragma unroll
    for (int n = 0; n < 2; n++)
      #pragma unroll
      for (int dt = 0; dt < 4; dt++)
        #pragma unroll
        for (int q = 0; q < 4; q++)
          r[(size_t)(n*16 + l4*4 + q)*OS_ + dt*16 + l15] = o[n][dt][q];
  }
  __syncthreads();
  if (kg == 0){
    float* r = smO + (size_t)g * 2112;
    float* og = Out + ((size_t)b*NQ_ + q0 + qh*32)*D_ + dh*64;
    #pragma unroll
    for (int n = 0; n < 2; n++)
      #pragma unroll
      for (int q = 0; q < 4; q++){
        int rowl = n*16 + l4*4 + q;              // row within q-half
        float lt = 0.f;
        #pragma unroll
        for (int w2 = 0; w2 < 8; w2++) lt += smL[w2*64 + qh*32 + rowl];
        float inv = 1.0f / lt;
        #pragma unroll
        for (int dt = 0; dt < 4; dt++){
          float val = o[n][dt][q] + r[(size_t)rowl*OS_ + dt*16 + l15];
          og[(size_t)rowl*D_ + dt*16 + l15] = val * inv;
        }
      }
  }
}

extern "C" void kernel_launch(void* const* d_in, const int* in_sizes, int n_in,
                              void* d_out, int out_size, void* d_ws, size_t ws_size,
                              hipStream_t stream){
  const float* q = (const float*)d_in[0];   // target [4,4096,128]
  const float* k = (const float*)d_in[1];   // key    [4,4096,128]
  const float* v = (const float*)d_in[2];   // value  [4,4096,128]
  float* out = (float*)d_out;
  unsigned short* kb = (unsigned short*)d_ws;          // K frag-major bf16, 4 MiB
  unsigned short* vt = kb + (size_t)B_*NK_*D_;         // V frag-major bf16, 4 MiB
  prep_kernel<<<256, 256, 0, stream>>>(k, v, kb, vt);
  attn_kernel<<<256, 1024, 0, stream>>>(q, kb, vt, out);
}

// Round 13
// 116.025 us; speedup vs baseline: 1.0698x; 1.0662x over previous
//
#include <hip/hip_runtime.h>
#include <stdint.h>

// Scaled-dot-product attention. B=4, NQ=NK=4096, D=128, fp32 in/out.
// R14: halve barrier frequency. R9-R13 falsified duplication/occupancy/VALU
// theories; R6's residual ~2000cy/iter is per-iter sync (lgkm drain + barrier
// skew + post-barrier LDS latency), paid once per tile. Restructure R6
// minimally: S(A)->bufA, S(B)->bufB, ONE lgkm+barrier, PV(A), PV(B).
// 4 P buffers rotating by round parity (pair reuse at r+2 fenced by barrier
// r+1, same argument as R6's dbuf). Register pressure and prefetch depth
// unchanged from R6 (A's s[] transients die before S(B)). Barriers 32->16.
// Spill canaries: FETCH ~12.4MB, WRITE ~8.2MB, VGPR 128.
#define B_ 4
#define NQ_ 4096
#define NK_ 4096
#define D_ 128
#define BM_ 64
#define BN_ 128
#define NITER_ (NK_/BN_)
#define PS_ 136        // P row stride (shorts): 272 B
#define OS_ 66         // epilogue O region row stride (floats)

typedef __attribute__((ext_vector_type(8))) short short8;
typedef __attribute__((ext_vector_type(4))) float floatx4;
typedef unsigned int u32;

union frag_u { u32 u[4]; short8 s; };
union pair_u { u32 u[2]; uint2 v; };

__device__ __forceinline__ unsigned short f2bf_rne(float x){
  union { float f; u32 u; } c; c.f = x;
  u32 u = c.u;
  return (unsigned short)((u + 0x7fffu + ((u >> 16) & 1u)) >> 16);
}
// pack 2 f32 -> 2 bf16 (round-half-up; bias << bf16 quantization)
__device__ __forceinline__ u32 pk2bf(float a, float b){
  union { float f; u32 u; } x, y; x.f = a; y.f = b;
  return ((x.u + 0x8000u) >> 16) | ((y.u + 0x8000u) & 0xffff0000u);
}

// ---- prep (unchanged from R7) ----
// Fragment layouts:
//  Kf chunk flat = (((b*32+it)*8 + wq)*4 + j)*64 + lane : 8 shorts =
//     K[b][it*128 + kg*32 + (l15>>2)*8 + dh*4 + (l15&3)][j*32 + l4*8 .. +8]
//  Vf chunk flat = (((b*32+it)*8 + wq)*4 + dt)*64 + lane : short kk(0..7) =
//     V[b][it*128 + kg*32 + l4*8 + kk][dh*64 + dt*16 + l15]   (wq = kg*2+dh)
__global__ __launch_bounds__(256) void prep_kernel(
    const float* __restrict__ k, const float* __restrict__ v,
    unsigned short* __restrict__ kf, unsigned short* __restrict__ vf){
  __shared__ __align__(16) char smem[40960];
  const int t = threadIdx.x;
  const int blk = blockIdx.x;
  if (blk < 128){
    // ---------------- K part ----------------
    int b = blk >> 5, it = blk & 31;
    const float* src = k + ((size_t)b*NK_ + it*BN_)*D_;
    #pragma unroll
    for (int i = 0; i < 16; i++){
      int f = t + i*256;                 // 0..4095 float4s
      int row = f >> 5, c4 = f & 31;     // row = local key, c4*4 = d
      float4 a = *(const float4*)(src + (size_t)row*D_ + c4*4);
      ushort4 s;
      s.x = f2bf_rne(a.x); s.y = f2bf_rne(a.y);
      s.z = f2bf_rne(a.z); s.w = f2bf_rne(a.w);
      int kg = row >> 5, rem = row & 31;
      int dh = (rem >> 2) & 1;
      int l15 = ((rem >> 3) << 2) | (rem & 3);
      int wq = kg*2 + dh;
      int j = c4 >> 3, l4 = (c4 >> 1) & 3, half = c4 & 1;
      *(ushort4*)(smem + (wq*4 + j)*1088 + l4*272 + l15*16 + half*8) = s;
    }
    __syncthreads();
    unsigned short* dst = kf + (size_t)(b*32 + it)*2048*8;
    #pragma unroll
    for (int i = 0; i < 8; i++){
      int c = t + i*256;                 // 0..2047 chunks
      int lane = c & 63, j = (c >> 6) & 3, wq = c >> 8;
      int l15 = lane & 15, l4 = lane >> 4;
      short8 x = *(const short8*)(smem + (wq*4 + j)*1088 + l4*272 + l15*16);
      *(short8*)(dst + (size_t)c*8) = x;
    }
  } else {
    // ---------------- V part ----------------
    int blk2 = blk - 128;
    int b = blk2 >> 5, it = blk2 & 31;
    const float* src = v + ((size_t)b*NK_ + it*BN_)*D_;
    #pragma unroll
    for (int i = 0; i < 16; i++){
      int f = t + i*256;
      int row = f >> 5, c4 = f & 31;
      float4 a = *(const float4*)(src + (size_t)row*D_ + c4*4);
      float vals[4] = {a.x, a.y, a.z, a.w};
      int kk = row & 7, l4a = (row >> 3) & 3, kga = row >> 5;
      #pragma unroll
      for (int jj = 0; jj < 4; jj++){
        int d = c4*4 + jj;
        int dh = d >> 6, dt = (d >> 4) & 3, l15 = d & 15;
        int c = ((kga*2 + dh)*4 + dt)*64 + l4a*16 + l15;
        *(unsigned short*)(smem + c*16 + (c>>2)*16 + kk*2) = f2bf_rne(vals[jj]);
      }
    }
    __syncthreads();
    unsigned short* dst = vf + (size_t)(b*32 + it)*2048*8;
    #pragma unroll
    for (int i = 0; i < 8; i++){
      int c = t + i*256;
      short8 x = *(const short8*)(smem + c*16 + (c>>2)*16);
      *(short8*)(dst + (size_t)c*8) = x;
    }
  }
}

// ---- main kernel ----
// grid 256 = B*NQ/64 (batch constant per XCD-pair -> K/V L2-resident);
// block 512 = 8 waves = (kg:4 key-groups) x (dh:2 d-halves).
// Round r: S(2r)->bufA, S(2r+1)->bufB, one raw barrier, PV(2r), PV(2r+1).
// K/V fragment loads 2 tiles deep in A/B register sets (issued after last use).
__global__ __launch_bounds__(512, 2) void attn_kernel(
    const float* __restrict__ Qf, const unsigned short* __restrict__ Kb,
    const unsigned short* __restrict__ Vt, float* __restrict__ Out){
  __shared__ __align__(16) char sm[71680];
  unsigned short* smP = (unsigned short*)sm;      // 4 x 64 x PS_ shorts = 69632 B
  float* smO = (float*)sm;                        // epilogue alias: 4 x 64 x OS_ floats
  float* smL = (float*)(sm + 69632);              // 8 x 64 f32 = 2048 B

  const int bi = blockIdx.x;
  const int b  = (bi >> 1) & 3;                 // batch constant per XCD-pair
  const int qt = ((bi >> 3) << 1) | (bi & 1);
  const int q0 = qt * BM_;
  const int tid = threadIdx.x;
  const int w = tid >> 6, lane = tid & 63;
  const int kg = w >> 1, dh = w & 1;
  const int l15 = lane & 15, l4 = lane >> 4;

  const short8* Kfrag = (const short8*)Kb;
  const short8* Vfrag = (const short8*)Vt;
  const size_t FSTRIDE = 8*4*64;                 // short8 units per K-tile iter
  const size_t fbase = (((size_t)b*32)*8 + w)*4*64 + lane;

  // ---- Q fragments direct from fp32 global ----
  short8 qf[4][4];
  {
    const float* qp = Qf + ((size_t)b*NQ_ + q0)*D_;
    #pragma unroll
    for (int nb = 0; nb < 4; nb++)
      #pragma unroll
      for (int kbq = 0; kbq < 4; kbq++){
        const float* p = qp + (size_t)(nb*16 + l15)*D_ + kbq*32 + l4*8;
        float4 a = *(const float4*)p;
        float4 c4 = *(const float4*)(p + 4);
        frag_u f;
        f.u[0] = pk2bf(a.x, a.y);  f.u[1] = pk2bf(a.z, a.w);
        f.u[2] = pk2bf(c4.x, c4.y); f.u[3] = pk2bf(c4.z, c4.w);
        qf[nb][kbq] = f.s;
      }
  }

  // ---- prologue: A set <- tile 0, B set <- tile 1 ----
  short8 kfA[4], kfB[4], vfA[4], vfB[4];
  #pragma unroll
  for (int j = 0; j < 4; j++) kfA[j] = Kfrag[fbase + j*64];
  #pragma unroll
  for (int dt = 0; dt < 4; dt++) vfA[dt] = Vfrag[fbase + dt*64];
  #pragma unroll
  for (int j = 0; j < 4; j++) kfB[j] = Kfrag[fbase + FSTRIDE + j*64];
  #pragma unroll
  for (int dt = 0; dt < 4; dt++) vfB[dt] = Vfrag[fbase + FSTRIDE + dt*64];

  floatx4 o[4][4];
  #pragma unroll
  for (int nb = 0; nb < 4; nb++)
    #pragma unroll
    for (int dt = 0; dt < 4; dt++) o[nb][dt] = (floatx4)0.0f;
  float lsum[4] = {0.f, 0.f, 0.f, 0.f};

  const float SL = 0.08838834764831845f * 1.4426950408889634f; // 1/sqrt(128)*log2(e)
  const size_t prow = (size_t)kg*32 + l4*8;

  for (int r = 0; r < NITER_/2; ++r){
    const int it = 2*r;
    unsigned short* bufA = smP + (size_t)(r & 1) * (2*64*PS_);
    unsigned short* bufB = bufA + 64*PS_;

    // ---- S(A): tile it -> bufA ----
    {
      floatx4 s[4];
      #pragma unroll
      for (int nb = 0; nb < 4; nb++){
        s[nb] = (floatx4)0.0f;
        s[nb] = __builtin_amdgcn_mfma_f32_16x16x32_bf16(kfA[0], qf[nb][0], s[nb], 0,0,0);
        s[nb] = __builtin_amdgcn_mfma_f32_16x16x32_bf16(kfA[1], qf[nb][1], s[nb], 0,0,0);
        s[nb] = __builtin_amdgcn_mfma_f32_16x16x32_bf16(kfA[2], qf[nb][2], s[nb], 0,0,0);
        s[nb] = __builtin_amdgcn_mfma_f32_16x16x32_bf16(kfA[3], qf[nb][3], s[nb], 0,0,0);
      }
      // prefetch K(it+2) -> A (kfA dead after S)
      if (it + 2 < NITER_){
        #pragma unroll
        for (int j = 0; j < 4; j++)
          kfA[j] = Kfrag[fbase + (size_t)(it+2)*FSTRIDE + j*64];
      }
      #pragma unroll
      for (int nb = 0; nb < 4; nb++){
        float p0 = __builtin_amdgcn_exp2f(s[nb][0] * SL);
        float p1 = __builtin_amdgcn_exp2f(s[nb][1] * SL);
        float p2 = __builtin_amdgcn_exp2f(s[nb][2] * SL);
        float p3 = __builtin_amdgcn_exp2f(s[nb][3] * SL);
        lsum[nb] += (p0 + p1) + (p2 + p3);
        pair_u pp; pp.u[0] = pk2bf(p0, p1); pp.u[1] = pk2bf(p2, p3);
        *(uint2*)(bufA + (size_t)(nb*16 + l15)*PS_ + prow + dh*4) = pp.v;
      }
    }
    // ---- S(B): tile it+1 -> bufB ----
    {
      floatx4 s[4];
      #pragma unroll
      for (int nb = 0; nb < 4; nb++){
        s[nb] = (floatx4)0.0f;
        s[nb] = __builtin_amdgcn_mfma_f32_16x16x32_bf16(kfB[0], qf[nb][0], s[nb], 0,0,0);
        s[nb] = __builtin_amdgcn_mfma_f32_16x16x32_bf16(kfB[1], qf[nb][1], s[nb], 0,0,0);
        s[nb] = __builtin_amdgcn_mfma_f32_16x16x32_bf16(kfB[2], qf[nb][2], s[nb], 0,0,0);
        s[nb] = __builtin_amdgcn_mfma_f32_16x16x32_bf16(kfB[3], qf[nb][3], s[nb], 0,0,0);
      }
      // prefetch K(it+3) -> B (kfB dead after S)
      if (it + 3 < NITER_){
        #pragma unroll
        for (int j = 0; j < 4; j++)
          kfB[j] = Kfrag[fbase + (size_t)(it+3)*FSTRIDE + j*64];
      }
      #pragma unroll
      for (int nb = 0; nb < 4; nb++){
        float p0 = __builtin_amdgcn_exp2f(s[nb][0] * SL);
        float p1 = __builtin_amdgcn_exp2f(s[nb][1] * SL);
        float p2 = __builtin_amdgcn_exp2f(s[nb][2] * SL);
        float p3 = __builtin_amdgcn_exp2f(s[nb][3] * SL);
        lsum[nb] += (p0 + p1) + (p2 + p3);
        pair_u pp; pp.u[0] = pk2bf(p0, p1); pp.u[1] = pk2bf(p2, p3);
        *(uint2*)(bufB + (size_t)(nb*16 + l15)*PS_ + prow + dh*4) = pp.v;
      }
    }

    // ---- ONE barrier for both tiles ----
    asm volatile("s_waitcnt lgkmcnt(0)" ::: "memory");
    __builtin_amdgcn_s_barrier();
    asm volatile("" ::: "memory");

    // ---- PV(A): tile it ----
    {
      short8 pf[4];
      #pragma unroll
      for (int nb = 0; nb < 4; nb++)
        pf[nb] = *(const short8*)(bufA + (size_t)(nb*16 + l15)*PS_ + prow);
      #pragma unroll
      for (int nb = 0; nb < 4; nb++)
        #pragma unroll
        for (int dt = 0; dt < 4; dt++)
          o[nb][dt] = __builtin_amdgcn_mfma_f32_16x16x32_bf16(pf[nb], vfA[dt], o[nb][dt], 0,0,0);
      // prefetch V(it+2) -> A (vfA dead after PV)
      if (it + 2 < NITER_){
        #pragma unroll
        for (int dt = 0; dt < 4; dt++)
          vfA[dt] = Vfrag[fbase + (size_t)(it+2)*FSTRIDE + dt*64];
      }
    }
    // ---- PV(B): tile it+1 ----
    {
      short8 pf[4];
      #pragma unroll
      for (int nb = 0; nb < 4; nb++)
        pf[nb] = *(const short8*)(bufB + (size_t)(nb*16 + l15)*PS_ + prow);
      #pragma unroll
      for (int nb = 0; nb < 4; nb++)
        #pragma unroll
        for (int dt = 0; dt < 4; dt++)
          o[nb][dt] = __builtin_amdgcn_mfma_f32_16x16x32_bf16(pf[nb], vfB[dt], o[nb][dt], 0,0,0);
      // prefetch V(it+3) -> B (vfB dead after PV)
      if (it + 3 < NITER_){
        #pragma unroll
        for (int dt = 0; dt < 4; dt++)
          vfB[dt] = Vfrag[fbase + (size_t)(it+3)*FSTRIDE + dt*64];
      }
    }
    // next round writes the OTHER buffer pair; this pair's reuse (round r+2)
    // is fenced by the barrier at round r+1.
  }

  // ---- epilogue: l reduce (once), O reduce over 4 key-groups, normalize, store ----
  #pragma unroll
  for (int nb = 0; nb < 4; nb++){
    float v = lsum[nb];
    v += __shfl_xor(v, 16);
    v += __shfl_xor(v, 32);
    lsum[nb] = v;
  }
  if (l4 == 0)
    #pragma unroll
    for (int nb = 0; nb < 4; nb++)
      smL[w*64 + nb*16 + l15] = lsum[nb];

  __syncthreads();   // all last-round P reads done before smO aliases the P region

  if (w >= 4){
    float* r = smO + (size_t)(w - 4) * 4224;
    #pragma unroll
    for (int nb = 0; nb < 4; nb++)
      #pragma unroll
      for (int dt = 0; dt < 4; dt++)
        #pragma unroll
        for (int q = 0; q < 4; q++)
          r[(size_t)(nb*16 + l4*4 + q)*OS_ + dt*16 + l15] = o[nb][dt][q];
  }
  __syncthreads();
  if (w < 4){
    float* r = smO + (size_t)w * 4224;
    #pragma unroll
    for (int nb = 0; nb < 4; nb++)
      #pragma unroll
      for (int dt = 0; dt < 4; dt++)
        #pragma unroll
        for (int q = 0; q < 4; q++)
          o[nb][dt][q] += r[(size_t)(nb*16 + l4*4 + q)*OS_ + dt*16 + l15];
  }
  __syncthreads();
  if (w == 2 || w == 3){
    float* r = smO + (size_t)(w - 2) * 4224;
    #pragma unroll
    for (int nb = 0; nb < 4; nb++)
      #pragma unroll
      for (int dt = 0; dt < 4; dt++)
        #pragma unroll
        for (int q = 0; q < 4; q++)
          r[(size_t)(nb*16 + l4*4 + q)*OS_ + dt*16 + l15] = o[nb][dt][q];
  }
  __syncthreads();
  if (w < 2){
    float* r = smO + (size_t)w * 4224;
    float* og = Out + ((size_t)b*NQ_ + q0)*D_ + dh*64;
    #pragma unroll
    for (int nb = 0; nb < 4; nb++)
      #pragma unroll
      for (int q = 0; q < 4; q++){
        int row = nb*16 + l4*4 + q;
        float lt = 0.f;
        #pragma unroll
        for (int w2 = 0; w2 < 8; w2++) lt += smL[w2*64 + row];
        float inv = 1.0f / lt;
        #pragma unroll
        for (int dt = 0; dt < 4; dt++){
          float val = o[nb][dt][q] + r[(size_t)row*OS_ + dt*16 + l15];
          og[(size_t)row*D_ + dt*16 + l15] = val * inv;
        }
      }
  }
}

extern "C" void kernel_launch(void* const* d_in, const int* in_sizes, int n_in,
                              void* d_out, int out_size, void* d_ws, size_t ws_size,
                              hipStream_t stream){
  const float* q = (const float*)d_in[0];   // target [4,4096,128]
  const float* k = (const float*)d_in[1];   // key    [4,4096,128]
  const float* v = (const float*)d_in[2];   // value  [4,4096,128]
  float* out = (float*)d_out;
  unsigned short* kb = (unsigned short*)d_ws;          // K frag-major bf16, 4 MiB
  unsigned short* vt = kb + (size_t)B_*NK_*D_;         // V frag-major bf16, 4 MiB
  prep_kernel<<<256, 256, 0, stream>>>(k, v, kb, vt);
  attn_kernel<<<256, 512, 0, stream>>>(q, kb, vt, out);
}

// Round 14
// 115.177 us; speedup vs baseline: 1.0777x; 1.0074x over previous
//
#include <hip/hip_runtime.h>
#include <stdint.h>

// Scaled-dot-product attention. B=4, NQ=NK=4096, D=128, fp32 in/out.
// R15: 4 tiles per barrier. R14 confirmed+calibrated the sync cost (~390cy
// per barrier event; 16 fewer barriers = -2.6us). Extend: S(A..D) -> 4 P
// buffers, ONE lgkm+barrier, PV(A..D). 8 buffers in 2 rotating sets (set
// reuse at r+2 fenced by barrier r+1). Registers unchanged (C/D reuse the
// A/B K/V reg sets via mid-phase prefetch: kfA reloaded after S(A) for
// S(C), cover ~500cy; vfA after PV(A) for PV(C), cover ~300cy; L2-resident).
// LDS 141KB (<160KB, occupancy already 1 block/CU). Barriers 16 -> 8.
// Spill canaries: FETCH ~12.4MB, WRITE ~8.2MB, VGPR 128.
#define B_ 4
#define NQ_ 4096
#define NK_ 4096
#define D_ 128
#define BM_ 64
#define BN_ 128
#define NITER_ (NK_/BN_)
#define PS_ 136        // P row stride (shorts): 272 B
#define OS_ 66         // epilogue O region row stride (floats)
#define PBUF_ (64*PS_) // one P buffer, in shorts (17408 B)

typedef __attribute__((ext_vector_type(8))) short short8;
typedef __attribute__((ext_vector_type(4))) float floatx4;
typedef unsigned int u32;

union frag_u { u32 u[4]; short8 s; };
union pair_u { u32 u[2]; uint2 v; };

__device__ __forceinline__ unsigned short f2bf_rne(float x){
  union { float f; u32 u; } c; c.f = x;
  u32 u = c.u;
  return (unsigned short)((u + 0x7fffu + ((u >> 16) & 1u)) >> 16);
}
// pack 2 f32 -> 2 bf16 (round-half-up; bias << bf16 quantization)
__device__ __forceinline__ u32 pk2bf(float a, float b){
  union { float f; u32 u; } x, y; x.f = a; y.f = b;
  return ((x.u + 0x8000u) >> 16) | ((y.u + 0x8000u) & 0xffff0000u);
}

// ---- prep (unchanged from R7) ----
// Fragment layouts:
//  Kf chunk flat = (((b*32+it)*8 + wq)*4 + j)*64 + lane : 8 shorts =
//     K[b][it*128 + kg*32 + (l15>>2)*8 + dh*4 + (l15&3)][j*32 + l4*8 .. +8]
//  Vf chunk flat = (((b*32+it)*8 + wq)*4 + dt)*64 + lane : short kk(0..7) =
//     V[b][it*128 + kg*32 + l4*8 + kk][dh*64 + dt*16 + l15]   (wq = kg*2+dh)
__global__ __launch_bounds__(256) void prep_kernel(
    const float* __restrict__ k, const float* __restrict__ v,
    unsigned short* __restrict__ kf, unsigned short* __restrict__ vf){
  __shared__ __align__(16) char smem[40960];
  const int t = threadIdx.x;
  const int blk = blockIdx.x;
  if (blk < 128){
    // ---------------- K part ----------------
    int b = blk >> 5, it = blk & 31;
    const float* src = k + ((size_t)b*NK_ + it*BN_)*D_;
    #pragma unroll
    for (int i = 0; i < 16; i++){
      int f = t + i*256;                 // 0..4095 float4s
      int row = f >> 5, c4 = f & 31;     // row = local key, c4*4 = d
      float4 a = *(const float4*)(src + (size_t)row*D_ + c4*4);
      ushort4 s;
      s.x = f2bf_rne(a.x); s.y = f2bf_rne(a.y);
      s.z = f2bf_rne(a.z); s.w = f2bf_rne(a.w);
      int kg = row >> 5, rem = row & 31;
      int dh = (rem >> 2) & 1;
      int l15 = ((rem >> 3) << 2) | (rem & 3);
      int wq = kg*2 + dh;
      int j = c4 >> 3, l4 = (c4 >> 1) & 3, half = c4 & 1;
      *(ushort4*)(smem + (wq*4 + j)*1088 + l4*272 + l15*16 + half*8) = s;
    }
    __syncthreads();
    unsigned short* dst = kf + (size_t)(b*32 + it)*2048*8;
    #pragma unroll
    for (int i = 0; i < 8; i++){
      int c = t + i*256;                 // 0..2047 chunks
      int lane = c & 63, j = (c >> 6) & 3, wq = c >> 8;
      int l15 = lane & 15, l4 = lane >> 4;
      short8 x = *(const short8*)(smem + (wq*4 + j)*1088 + l4*272 + l15*16);
      *(short8*)(dst + (size_t)c*8) = x;
    }
  } else {
    // ---------------- V part ----------------
    int blk2 = blk - 128;
    int b = blk2 >> 5, it = blk2 & 31;
    const float* src = v + ((size_t)b*NK_ + it*BN_)*D_;
    #pragma unroll
    for (int i = 0; i < 16; i++){
      int f = t + i*256;
      int row = f >> 5, c4 = f & 31;
      float4 a = *(const float4*)(src + (size_t)row*D_ + c4*4);
      float vals[4] = {a.x, a.y, a.z, a.w};
      int kk = row & 7, l4a = (row >> 3) & 3, kga = row >> 5;
      #pragma unroll
      for (int jj = 0; jj < 4; jj++){
        int d = c4*4 + jj;
        int dh = d >> 6, dt = (d >> 4) & 3, l15 = d & 15;
        int c = ((kga*2 + dh)*4 + dt)*64 + l4a*16 + l15;
        *(unsigned short*)(smem + c*16 + (c>>2)*16 + kk*2) = f2bf_rne(vals[jj]);
      }
    }
    __syncthreads();
    unsigned short* dst = vf + (size_t)(b*32 + it)*2048*8;
    #pragma unroll
    for (int i = 0; i < 8; i++){
      int c = t + i*256;
      short8 x = *(const short8*)(smem + c*16 + (c>>2)*16);
      *(short8*)(dst + (size_t)c*8) = x;
    }
  }
}

// S-phase: tile consumed from KF, P written to BUF, then KF <- tile PFIT.
#define SPH(KF, BUF, PFIT) do {                                                \
  floatx4 s[4];                                                                \
  _Pragma("unroll")                                                            \
  for (int nb = 0; nb < 4; nb++){                                              \
    s[nb] = (floatx4)0.0f;                                                     \
    s[nb] = __builtin_amdgcn_mfma_f32_16x16x32_bf16(KF[0], qf[nb][0], s[nb],0,0,0);\
    s[nb] = __builtin_amdgcn_mfma_f32_16x16x32_bf16(KF[1], qf[nb][1], s[nb],0,0,0);\
    s[nb] = __builtin_amdgcn_mfma_f32_16x16x32_bf16(KF[2], qf[nb][2], s[nb],0,0,0);\
    s[nb] = __builtin_amdgcn_mfma_f32_16x16x32_bf16(KF[3], qf[nb][3], s[nb],0,0,0);\
  }                                                                            \
  if ((PFIT) < NITER_){                                                        \
    _Pragma("unroll")                                                          \
    for (int j = 0; j < 4; j++)                                                \
      KF[j] = Kfrag[fbase + (size_t)(PFIT)*FSTRIDE + j*64];                    \
  }                                                                            \
  _Pragma("unroll")                                                            \
  for (int nb = 0; nb < 4; nb++){                                              \
    float p0 = __builtin_amdgcn_exp2f(s[nb][0] * SL);                          \
    float p1 = __builtin_amdgcn_exp2f(s[nb][1] * SL);                          \
    float p2 = __builtin_amdgcn_exp2f(s[nb][2] * SL);                          \
    float p3 = __builtin_amdgcn_exp2f(s[nb][3] * SL);                          \
    lsum[nb] += (p0 + p1) + (p2 + p3);                                         \
    pair_u pp; pp.u[0] = pk2bf(p0, p1); pp.u[1] = pk2bf(p2, p3);               \
    *(uint2*)((BUF) + (size_t)(nb*16 + l15)*PS_ + prow + dh*4) = pp.v;         \
  }                                                                            \
} while(0)

// PV-phase: P read from BUF, O += P*V with VF, then VF <- tile PFIT.
#define PVPH(VF, BUF, PFIT) do {                                               \
  short8 pf[4];                                                                \
  _Pragma("unroll")                                                            \
  for (int nb = 0; nb < 4; nb++)                                               \
    pf[nb] = *(const short8*)((BUF) + (size_t)(nb*16 + l15)*PS_ + prow);       \
  _Pragma("unroll")                                                            \
  for (int nb = 0; nb < 4; nb++)                                               \
    _Pragma("unroll")                                                          \
    for (int dt = 0; dt < 4; dt++)                                             \
      o[nb][dt] = __builtin_amdgcn_mfma_f32_16x16x32_bf16(pf[nb], VF[dt], o[nb][dt],0,0,0);\
  if ((PFIT) < NITER_){                                                        \
    _Pragma("unroll")                                                          \
    for (int dt = 0; dt < 4; dt++)                                             \
      VF[dt] = Vfrag[fbase + (size_t)(PFIT)*FSTRIDE + dt*64];                  \
  }                                                                            \
} while(0)

// ---- main kernel ----
// grid 256 = B*NQ/64 (batch constant per XCD-pair -> K/V L2-resident);
// block 512 = 8 waves = (kg:4 key-groups) x (dh:2 d-halves).
// Round r (it=4r): S(it..it+3) -> bufs 0..3 of set (r&1), ONE raw barrier,
// PV(it..it+3). K/V reg sets A/B reused by C/D via mid-phase prefetch.
__global__ __launch_bounds__(512, 2) void attn_kernel(
    const float* __restrict__ Qf, const unsigned short* __restrict__ Kb,
    const unsigned short* __restrict__ Vt, float* __restrict__ Out){
  __shared__ __align__(16) char sm[141312];
  unsigned short* smP = (unsigned short*)sm;      // 8 x 64 x PS_ shorts = 139264 B
  float* smO = (float*)sm;                        // epilogue alias: 4 x 64 x OS_ floats
  float* smL = (float*)(sm + 139264);             // 8 x 64 f32 = 2048 B

  const int bi = blockIdx.x;
  const int b  = (bi >> 1) & 3;                 // batch constant per XCD-pair
  const int qt = ((bi >> 3) << 1) | (bi & 1);
  const int q0 = qt * BM_;
  const int tid = threadIdx.x;
  const int w = tid >> 6, lane = tid & 63;
  const int kg = w >> 1, dh = w & 1;
  const int l15 = lane & 15, l4 = lane >> 4;

  const short8* Kfrag = (const short8*)Kb;
  const short8* Vfrag = (const short8*)Vt;
  const size_t FSTRIDE = 8*4*64;                 // short8 units per K-tile iter
  const size_t fbase = (((size_t)b*32)*8 + w)*4*64 + lane;

  // ---- Q fragments direct from fp32 global ----
  short8 qf[4][4];
  {
    const float* qp = Qf + ((size_t)b*NQ_ + q0)*D_;
    #pragma unroll
    for (int nb = 0; nb < 4; nb++)
      #pragma unroll
      for (int kbq = 0; kbq < 4; kbq++){
        const float* p = qp + (size_t)(nb*16 + l15)*D_ + kbq*32 + l4*8;
        float4 a = *(const float4*)p;
        float4 c4 = *(const float4*)(p + 4);
        frag_u f;
        f.u[0] = pk2bf(a.x, a.y);  f.u[1] = pk2bf(a.z, a.w);
        f.u[2] = pk2bf(c4.x, c4.y); f.u[3] = pk2bf(c4.z, c4.w);
        qf[nb][kbq] = f.s;
      }
  }

  // ---- prologue: A set <- tile 0, B set <- tile 1 ----
  short8 kfA[4], kfB[4], vfA[4], vfB[4];
  #pragma unroll
  for (int j = 0; j < 4; j++) kfA[j] = Kfrag[fbase + j*64];
  #pragma unroll
  for (int dt = 0; dt < 4; dt++) vfA[dt] = Vfrag[fbase + dt*64];
  #pragma unroll
  for (int j = 0; j < 4; j++) kfB[j] = Kfrag[fbase + FSTRIDE + j*64];
  #pragma unroll
  for (int dt = 0; dt < 4; dt++) vfB[dt] = Vfrag[fbase + FSTRIDE + dt*64];

  floatx4 o[4][4];
  #pragma unroll
  for (int nb = 0; nb < 4; nb++)
    #pragma unroll
    for (int dt = 0; dt < 4; dt++) o[nb][dt] = (floatx4)0.0f;
  float lsum[4] = {0.f, 0.f, 0.f, 0.f};

  const float SL = 0.08838834764831845f * 1.4426950408889634f; // 1/sqrt(128)*log2(e)
  const size_t prow = (size_t)kg*32 + l4*8;

  for (int r = 0; r < NITER_/4; ++r){
    const int it = 4*r;
    unsigned short* base = smP + (size_t)(r & 1) * (4*PBUF_);

    // ---- S phases: 4 tiles -> 4 buffers; A/B reg sets reused by C/D ----
    SPH(kfA, base + 0*PBUF_, it+2);   // S(it)   uses kfA(it),   kfA <- it+2
    SPH(kfB, base + 1*PBUF_, it+3);   // S(it+1) uses kfB(it+1), kfB <- it+3
    SPH(kfA, base + 2*PBUF_, it+4);   // S(it+2) uses kfA(it+2), kfA <- it+4
    SPH(kfB, base + 3*PBUF_, it+5);   // S(it+3) uses kfB(it+3), kfB <- it+5

    // ---- ONE barrier for all four tiles ----
    asm volatile("s_waitcnt lgkmcnt(0)" ::: "memory");
    __builtin_amdgcn_s_barrier();
    asm volatile("" ::: "memory");

    // ---- PV phases ----
    PVPH(vfA, base + 0*PBUF_, it+2);  // PV(it)   uses vfA(it),   vfA <- it+2
    PVPH(vfB, base + 1*PBUF_, it+3);  // PV(it+1) uses vfB(it+1), vfB <- it+3
    PVPH(vfA, base + 2*PBUF_, it+4);  // PV(it+2) uses vfA(it+2), vfA <- it+4
    PVPH(vfB, base + 3*PBUF_, it+5);  // PV(it+3) uses vfB(it+3), vfB <- it+5

    // next round writes the OTHER 4-buffer set; this set's reuse (round r+2)
    // is fenced by the barrier at round r+1.
  }

  // ---- epilogue: l reduce (once), O reduce over 4 key-groups, normalize, store ----
  #pragma unroll
  for (int nb = 0; nb < 4; nb++){
    float v = lsum[nb];
    v += __shfl_xor(v, 16);
    v += __shfl_xor(v, 32);
    lsum[nb] = v;
  }
  if (l4 == 0)
    #pragma unroll
    for (int nb = 0; nb < 4; nb++)
      smL[w*64 + nb*16 + l15] = lsum[nb];

  __syncthreads();   // all last-round P reads done before smO aliases the P region

  if (w >= 4){
    float* r = smO + (size_t)(w - 4) * 4224;
    #pragma unroll
    for (int nb = 0; nb < 4; nb++)
      #pragma unroll
      for (int dt = 0; dt < 4; dt++)
        #pragma unroll
        for (int q = 0; q < 4; q++)
          r[(size_t)(nb*16 + l4*4 + q)*OS_ + dt*16 + l15] = o[nb][dt][q];
  }
  __syncthreads();
  if (w < 4){
    float* r = smO + (size_t)w * 4224;
    #pragma unroll
    for (int nb = 0; nb < 4; nb++)
      #pragma unroll
      for (int dt = 0; dt < 4; dt++)
        #pragma unroll
        for (int q = 0; q < 4; q++)
          o[nb][dt][q] += r[(size_t)(nb*16 + l4*4 + q)*OS_ + dt*16 + l15];
  }
  __syncthreads();
  if (w == 2 || w == 3){
    float* r = smO + (size_t)(w - 2) * 4224;
    #pragma unroll
    for (int nb = 0; nb < 4; nb++)
      #pragma unroll
      for (int dt = 0; dt < 4; dt++)
        #pragma unroll
        for (int q = 0; q < 4; q++)
          r[(size_t)(nb*16 + l4*4 + q)*OS_ + dt*16 + l15] = o[nb][dt][q];
  }
  __syncthreads();
  if (w < 2){
    float* r = smO + (size_t)w * 4224;
    float* og = Out + ((size_t)b*NQ_ + q0)*D_ + dh*64;
    #pragma unroll
    for (int nb = 0; nb < 4; nb++)
      #pragma unroll
      for (int q = 0; q < 4; q++){
        int row = nb*16 + l4*4 + q;
        float lt = 0.f;
        #pragma unroll
        for (int w2 = 0; w2 < 8; w2++) lt += smL[w2*64 + row];
        float inv = 1.0f / lt;
        #pragma unroll
        for (int dt = 0; dt < 4; dt++){
          float val = o[nb][dt][q] + r[(size_t)row*OS_ + dt*16 + l15];
          og[(size_t)row*D_ + dt*16 + l15] = val * inv;
        }
      }
  }
}

extern "C" void kernel_launch(void* const* d_in, const int* in_sizes, int n_in,
                              void* d_out, int out_size, void* d_ws, size_t ws_size,
                              hipStream_t stream){
  const float* q = (const float*)d_in[0];   // target [4,4096,128]
  const float* k = (const float*)d_in[1];   // key    [4,4096,128]
  const float* v = (const float*)d_in[2];   // value  [4,4096,128]
  float* out = (float*)d_out;
  unsigned short* kb = (unsigned short*)d_ws;          // K frag-major bf16, 4 MiB
  unsigned short* vt = kb + (size_t)B_*NK_*D_;         // V frag-major bf16, 4 MiB
  prep_kernel<<<256, 256, 0, stream>>>(k, v, kb, vt);
  attn_kernel<<<256, 512, 0, stream>>>(q, kb, vt, out);
}

// Round 15
// 114.483 us; speedup vs baseline: 1.0842x; 1.0061x over previous
//
#include <hip/hip_runtime.h>
#include <stdint.h>

// Scaled-dot-product attention. B=4, NQ=NK=4096, D=128, fp32 in/out.
// R16: attn = R14 VERBATIM (best clean state: 48.7us, FETCH 12.4MB, VGPR 128;
// R15's 4-tiles-per-barrier extended K/V live ranges -> spills -> revert).
// prep: V-part writes paired — each thread converts rows (2rp, 2rp+1) at the
// same d, so two ds_write_b16 merge into one aligned ds_write_b32 (kk0 even).
// Output bytes identical; global loads stay coalesced (2x512B per wave-instr).
#define B_ 4
#define NQ_ 4096
#define NK_ 4096
#define D_ 128
#define BM_ 64
#define BN_ 128
#define NITER_ (NK_/BN_)
#define PS_ 136        // P row stride (shorts): 272 B
#define OS_ 66         // epilogue O region row stride (floats)

typedef __attribute__((ext_vector_type(8))) short short8;
typedef __attribute__((ext_vector_type(4))) float floatx4;
typedef unsigned int u32;

union frag_u { u32 u[4]; short8 s; };
union pair_u { u32 u[2]; uint2 v; };

__device__ __forceinline__ unsigned short f2bf_rne(float x){
  union { float f; u32 u; } c; c.f = x;
  u32 u = c.u;
  return (unsigned short)((u + 0x7fffu + ((u >> 16) & 1u)) >> 16);
}
// pack 2 f32 -> 2 bf16 (round-half-up; bias << bf16 quantization)
__device__ __forceinline__ u32 pk2bf(float a, float b){
  union { float f; u32 u; } x, y; x.f = a; y.f = b;
  return ((x.u + 0x8000u) >> 16) | ((y.u + 0x8000u) & 0xffff0000u);
}

// ---- prep ----
// Fragment layouts (identical bytes to R7):
//  Kf chunk flat = (((b*32+it)*8 + wq)*4 + j)*64 + lane : 8 shorts =
//     K[b][it*128 + kg*32 + (l15>>2)*8 + dh*4 + (l15&3)][j*32 + l4*8 .. +8]
//  Vf chunk flat = (((b*32+it)*8 + wq)*4 + dt)*64 + lane : short kk(0..7) =
//     V[b][it*128 + kg*32 + l4*8 + kk][dh*64 + dt*16 + l15]   (wq = kg*2+dh)
__global__ __launch_bounds__(256) void prep_kernel(
    const float* __restrict__ k, const float* __restrict__ v,
    unsigned short* __restrict__ kf, unsigned short* __restrict__ vf){
  __shared__ __align__(16) char smem[40960];
  const int t = threadIdx.x;
  const int blk = blockIdx.x;
  if (blk < 128){
    // ---------------- K part ----------------
    int b = blk >> 5, it = blk & 31;
    const float* src = k + ((size_t)b*NK_ + it*BN_)*D_;
    #pragma unroll
    for (int i = 0; i < 16; i++){
      int f = t + i*256;                 // 0..4095 float4s
      int row = f >> 5, c4 = f & 31;     // row = local key, c4*4 = d
      float4 a = *(const float4*)(src + (size_t)row*D_ + c4*4);
      ushort4 s;
      s.x = f2bf_rne(a.x); s.y = f2bf_rne(a.y);
      s.z = f2bf_rne(a.z); s.w = f2bf_rne(a.w);
      int kg = row >> 5, rem = row & 31;
      int dh = (rem >> 2) & 1;
      int l15 = ((rem >> 3) << 2) | (rem & 3);
      int wq = kg*2 + dh;
      int j = c4 >> 3, l4 = (c4 >> 1) & 3, half = c4 & 1;
      *(ushort4*)(smem + (wq*4 + j)*1088 + l4*272 + l15*16 + half*8) = s;
    }
    __syncthreads();
    unsigned short* dst = kf + (size_t)(b*32 + it)*2048*8;
    #pragma unroll
    for (int i = 0; i < 8; i++){
      int c = t + i*256;                 // 0..2047 chunks
      int lane = c & 63, j = (c >> 6) & 3, wq = c >> 8;
      int l15 = lane & 15, l4 = lane >> 4;
      short8 x = *(const short8*)(smem + (wq*4 + j)*1088 + l4*272 + l15*16);
      *(short8*)(dst + (size_t)c*8) = x;
    }
  } else {
    // ---------------- V part (paired-row b32 writes) ----------------
    int blk2 = blk - 128;
    int b = blk2 >> 5, it = blk2 & 31;
    const float* src = v + ((size_t)b*NK_ + it*BN_)*D_;
    #pragma unroll
    for (int i = 0; i < 8; i++){
      int u2 = t + i*256;                // 0..2047 (row-pair, c4) items
      int rp = u2 >> 5, c4 = u2 & 31;    // rp = 0..63, c4*4 = d
      int r0 = rp*2;                     // rows r0, r0+1 share kga/l4a; kk0 even
      const float* p0r = src + (size_t)r0*D_ + c4*4;
      float4 a0 = *(const float4*)p0r;
      float4 a1 = *(const float4*)(p0r + D_);
      int kk0 = r0 & 7;
      int l4a = (r0 >> 3) & 3, kga = r0 >> 5;
      float v0[4] = {a0.x, a0.y, a0.z, a0.w};
      float v1[4] = {a1.x, a1.y, a1.z, a1.w};
      #pragma unroll
      for (int jj = 0; jj < 4; jj++){
        int d = c4*4 + jj;
        int dh = d >> 6, dt = (d >> 4) & 3, l15 = d & 15;
        int c = ((kga*2 + dh)*4 + dt)*64 + l4a*16 + l15;
        ushort2 s2; s2.x = f2bf_rne(v0[jj]); s2.y = f2bf_rne(v1[jj]);
        *(ushort2*)(smem + c*16 + (c>>2)*16 + kk0*2) = s2;
      }
    }
    __syncthreads();
    unsigned short* dst = vf + (size_t)(b*32 + it)*2048*8;
    #pragma unroll
    for (int i = 0; i < 8; i++){
      int c = t + i*256;
      short8 x = *(const short8*)(smem + c*16 + (c>>2)*16);
      *(short8*)(dst + (size_t)c*8) = x;
    }
  }
}

// ---- main kernel (R14 verbatim) ----
// grid 256 = B*NQ/64 (batch constant per XCD-pair -> K/V L2-resident);
// block 512 = 8 waves = (kg:4 key-groups) x (dh:2 d-halves).
// Round r: S(2r)->bufA, S(2r+1)->bufB, one raw barrier, PV(2r), PV(2r+1).
// K/V fragment loads 2 tiles deep in A/B register sets (issued after last use).
__global__ __launch_bounds__(512, 2) void attn_kernel(
    const float* __restrict__ Qf, const unsigned short* __restrict__ Kb,
    const unsigned short* __restrict__ Vt, float* __restrict__ Out){
  __shared__ __align__(16) char sm[71680];
  unsigned short* smP = (unsigned short*)sm;      // 4 x 64 x PS_ shorts = 69632 B
  float* smO = (float*)sm;                        // epilogue alias: 4 x 64 x OS_ floats
  float* smL = (float*)(sm + 69632);              // 8 x 64 f32 = 2048 B

  const int bi = blockIdx.x;
  const int b  = (bi >> 1) & 3;                 // batch constant per XCD-pair
  const int qt = ((bi >> 3) << 1) | (bi & 1);
  const int q0 = qt * BM_;
  const int tid = threadIdx.x;
  const int w = tid >> 6, lane = tid & 63;
  const int kg = w >> 1, dh = w & 1;
  const int l15 = lane & 15, l4 = lane >> 4;

  const short8* Kfrag = (const short8*)Kb;
  const short8* Vfrag = (const short8*)Vt;
  const size_t FSTRIDE = 8*4*64;                 // short8 units per K-tile iter
  const size_t fbase = (((size_t)b*32)*8 + w)*4*64 + lane;

  // ---- Q fragments direct from fp32 global ----
  short8 qf[4][4];
  {
    const float* qp = Qf + ((size_t)b*NQ_ + q0)*D_;
    #pragma unroll
    for (int nb = 0; nb < 4; nb++)
      #pragma unroll
      for (int kbq = 0; kbq < 4; kbq++){
        const float* p = qp + (size_t)(nb*16 + l15)*D_ + kbq*32 + l4*8;
        float4 a = *(const float4*)p;
        float4 c4 = *(const float4*)(p + 4);
        frag_u f;
        f.u[0] = pk2bf(a.x, a.y);  f.u[1] = pk2bf(a.z, a.w);
        f.u[2] = pk2bf(c4.x, c4.y); f.u[3] = pk2bf(c4.z, c4.w);
        qf[nb][kbq] = f.s;
      }
  }

  // ---- prologue: A set <- tile 0, B set <- tile 1 ----
  short8 kfA[4], kfB[4], vfA[4], vfB[4];
  #pragma unroll
  for (int j = 0; j < 4; j++) kfA[j] = Kfrag[fbase + j*64];
  #pragma unroll
  for (int dt = 0; dt < 4; dt++) vfA[dt] = Vfrag[fbase + dt*64];
  #pragma unroll
  for (int j = 0; j < 4; j++) kfB[j] = Kfrag[fbase + FSTRIDE + j*64];
  #pragma unroll
  for (int dt = 0; dt < 4; dt++) vfB[dt] = Vfrag[fbase + FSTRIDE + dt*64];

  floatx4 o[4][4];
  #pragma unroll
  for (int nb = 0; nb < 4; nb++)
    #pragma unroll
    for (int dt = 0; dt < 4; dt++) o[nb][dt] = (floatx4)0.0f;
  float lsum[4] = {0.f, 0.f, 0.f, 0.f};

  const float SL = 0.08838834764831845f * 1.4426950408889634f; // 1/sqrt(128)*log2(e)
  const size_t prow = (size_t)kg*32 + l4*8;

  for (int r = 0; r < NITER_/2; ++r){
    const int it = 2*r;
    unsigned short* bufA = smP + (size_t)(r & 1) * (2*64*PS_);
    unsigned short* bufB = bufA + 64*PS_;

    // ---- S(A): tile it -> bufA ----
    {
      floatx4 s[4];
      #pragma unroll
      for (int nb = 0; nb < 4; nb++){
        s[nb] = (floatx4)0.0f;
        s[nb] = __builtin_amdgcn_mfma_f32_16x16x32_bf16(kfA[0], qf[nb][0], s[nb], 0,0,0);
        s[nb] = __builtin_amdgcn_mfma_f32_16x16x32_bf16(kfA[1], qf[nb][1], s[nb], 0,0,0);
        s[nb] = __builtin_amdgcn_mfma_f32_16x16x32_bf16(kfA[2], qf[nb][2], s[nb], 0,0,0);
        s[nb] = __builtin_amdgcn_mfma_f32_16x16x32_bf16(kfA[3], qf[nb][3], s[nb], 0,0,0);
      }
      // prefetch K(it+2) -> A (kfA dead after S)
      if (it + 2 < NITER_){
        #pragma unroll
        for (int j = 0; j < 4; j++)
          kfA[j] = Kfrag[fbase + (size_t)(it+2)*FSTRIDE + j*64];
      }
      #pragma unroll
      for (int nb = 0; nb < 4; nb++){
        float p0 = __builtin_amdgcn_exp2f(s[nb][0] * SL);
        float p1 = __builtin_amdgcn_exp2f(s[nb][1] * SL);
        float p2 = __builtin_amdgcn_exp2f(s[nb][2] * SL);
        float p3 = __builtin_amdgcn_exp2f(s[nb][3] * SL);
        lsum[nb] += (p0 + p1) + (p2 + p3);
        pair_u pp; pp.u[0] = pk2bf(p0, p1); pp.u[1] = pk2bf(p2, p3);
        *(uint2*)(bufA + (size_t)(nb*16 + l15)*PS_ + prow + dh*4) = pp.v;
      }
    }
    // ---- S(B): tile it+1 -> bufB ----
    {
      floatx4 s[4];
      #pragma unroll
      for (int nb = 0; nb < 4; nb++){
        s[nb] = (floatx4)0.0f;
        s[nb] = __builtin_amdgcn_mfma_f32_16x16x32_bf16(kfB[0], qf[nb][0], s[nb], 0,0,0);
        s[nb] = __builtin_amdgcn_mfma_f32_16x16x32_bf16(kfB[1], qf[nb][1], s[nb], 0,0,0);
        s[nb] = __builtin_amdgcn_mfma_f32_16x16x32_bf16(kfB[2], qf[nb][2], s[nb], 0,0,0);
        s[nb] = __builtin_amdgcn_mfma_f32_16x16x32_bf16(kfB[3], qf[nb][3], s[nb], 0,0,0);
      }
      // prefetch K(it+3) -> B (kfB dead after S)
      if (it + 3 < NITER_){
        #pragma unroll
        for (int j = 0; j < 4; j++)
          kfB[j] = Kfrag[fbase + (size_t)(it+3)*FSTRIDE + j*64];
      }
      #pragma unroll
      for (int nb = 0; nb < 4; nb++){
        float p0 = __builtin_amdgcn_exp2f(s[nb][0] * SL);
        float p1 = __builtin_amdgcn_exp2f(s[nb][1] * SL);
        float p2 = __builtin_amdgcn_exp2f(s[nb][2] * SL);
        float p3 = __builtin_amdgcn_exp2f(s[nb][3] * SL);
        lsum[nb] += (p0 + p1) + (p2 + p3);
        pair_u pp; pp.u[0] = pk2bf(p0, p1); pp.u[1] = pk2bf(p2, p3);
        *(uint2*)(bufB + (size_t)(nb*16 + l15)*PS_ + prow + dh*4) = pp.v;
      }
    }

    // ---- ONE barrier for both tiles ----
    asm volatile("s_waitcnt lgkmcnt(0)" ::: "memory");
    __builtin_amdgcn_s_barrier();
    asm volatile("" ::: "memory");

    // ---- PV(A): tile it ----
    {
      short8 pf[4];
      #pragma unroll
      for (int nb = 0; nb < 4; nb++)
        pf[nb] = *(const short8*)(bufA + (size_t)(nb*16 + l15)*PS_ + prow);
      #pragma unroll
      for (int nb = 0; nb < 4; nb++)
        #pragma unroll
        for (int dt = 0; dt < 4; dt++)
          o[nb][dt] = __builtin_amdgcn_mfma_f32_16x16x32_bf16(pf[nb], vfA[dt], o[nb][dt], 0,0,0);
      // prefetch V(it+2) -> A (vfA dead after PV)
      if (it + 2 < NITER_){
        #pragma unroll
        for (int dt = 0; dt < 4; dt++)
          vfA[dt] = Vfrag[fbase + (size_t)(it+2)*FSTRIDE + dt*64];
      }
    }
    // ---- PV(B): tile it+1 ----
    {
      short8 pf[4];
      #pragma unroll
      for (int nb = 0; nb < 4; nb++)
        pf[nb] = *(const short8*)(bufB + (size_t)(nb*16 + l15)*PS_ + prow);
      #pragma unroll
      for (int nb = 0; nb < 4; nb++)
        #pragma unroll
        for (int dt = 0; dt < 4; dt++)
          o[nb][dt] = __builtin_amdgcn_mfma_f32_16x16x32_bf16(pf[nb], vfB[dt], o[nb][dt], 0,0,0);
      // prefetch V(it+3) -> B (vfB dead after PV)
      if (it + 3 < NITER_){
        #pragma unroll
        for (int dt = 0; dt < 4; dt++)
          vfB[dt] = Vfrag[fbase + (size_t)(it+3)*FSTRIDE + dt*64];
      }
    }
    // next round writes the OTHER buffer pair; this pair's reuse (round r+2)
    // is fenced by the barrier at round r+1.
  }

  // ---- epilogue: l reduce (once), O reduce over 4 key-groups, normalize, store ----
  #pragma unroll
  for (int nb = 0; nb < 4; nb++){
    float v = lsum[nb];
    v += __shfl_xor(v, 16);
    v += __shfl_xor(v, 32);
    lsum[nb] = v;
  }
  if (l4 == 0)
    #pragma unroll
    for (int nb = 0; nb < 4; nb++)
      smL[w*64 + nb*16 + l15] = lsum[nb];

  __syncthreads();   // all last-round P reads done before smO aliases the P region

  if (w >= 4){
    float* r = smO + (size_t)(w - 4) * 4224;
    #pragma unroll
    for (int nb = 0; nb < 4; nb++)
      #pragma unroll
      for (int dt = 0; dt < 4; dt++)
        #pragma unroll
        for (int q = 0; q < 4; q++)
          r[(size_t)(nb*16 + l4*4 + q)*OS_ + dt*16 + l15] = o[nb][dt][q];
  }
  __syncthreads();
  if (w < 4){
    float* r = smO + (size_t)w * 4224;
    #pragma unroll
    for (int nb = 0; nb < 4; nb++)
      #pragma unroll
      for (int dt = 0; dt < 4; dt++)
        #pragma unroll
        for (int q = 0; q < 4; q++)
          o[nb][dt][q] += r[(size_t)(nb*16 + l4*4 + q)*OS_ + dt*16 + l15];
  }
  __syncthreads();
  if (w == 2 || w == 3){
    float* r = smO + (size_t)(w - 2) * 4224;
    #pragma unroll
    for (int nb = 0; nb < 4; nb++)
      #pragma unroll
      for (int dt = 0; dt < 4; dt++)
        #pragma unroll
        for (int q = 0; q < 4; q++)
          r[(size_t)(nb*16 + l4*4 + q)*OS_ + dt*16 + l15] = o[nb][dt][q];
  }
  __syncthreads();
  if (w < 2){
    float* r = smO + (size_t)w * 4224;
    float* og = Out + ((size_t)b*NQ_ + q0)*D_ + dh*64;
    #pragma unroll
    for (int nb = 0; nb < 4; nb++)
      #pragma unroll
      for (int q = 0; q < 4; q++){
        int row = nb*16 + l4*4 + q;
        float lt = 0.f;
        #pragma unroll
        for (int w2 = 0; w2 < 8; w2++) lt += smL[w2*64 + row];
        float inv = 1.0f / lt;
        #pragma unroll
        for (int dt = 0; dt < 4; dt++){
          float val = o[nb][dt][q] + r[(size_t)row*OS_ + dt*16 + l15];
          og[(size_t)row*D_ + dt*16 + l15] = val * inv;
        }
      }
  }
}

extern "C" void kernel_launch(void* const* d_in, const int* in_sizes, int n_in,
                              void* d_out, int out_size, void* d_ws, size_t ws_size,
                              hipStream_t stream){
  const float* q = (const float*)d_in[0];   // target [4,4096,128]
  const float* k = (const float*)d_in[1];   // key    [4,4096,128]
  const float* v = (const float*)d_in[2];   // value  [4,4096,128]
  float* out = (float*)d_out;
  unsigned short* kb = (unsigned short*)d_ws;          // K frag-major bf16, 4 MiB
  unsigned short* vt = kb + (size_t)B_*NK_*D_;         // V frag-major bf16, 4 MiB
  prep_kernel<<<256, 256, 0, stream>>>(k, v, kb, vt);
  attn_kernel<<<256, 512, 0, stream>>>(q, kb, vt, out);
}